// Round 4
// baseline (520.465 us; speedup 1.0000x reference)
//
#include <hip/hip_runtime.h>
#include <stdint.h>

// ---------------------------------------------------------------------------
// Attention_18116172054662 on MI355X (gfx950)
//   L = tgt @ src^T  (split-bf16 triple MFMA for f32-grade logits)
//   weight = softmax(L, axis=tgt)   -> second output (f32, in place in d_out)
//   weight_sum = weight @ src       (bf16 MFMA, NT via pre-transposed src)
//   out = [weight_sum | tgt] @ W^T + b   (bf16 MFMA NT)
// R1: global_load_lds width-16 staging, fused column stats, vectorized EW.
// R2: XOR-swizzled LDS (zero bank conflicts; proved LDS wasn't the limiter).
// R3: software-pipelined K-loop: A double-buffered in LDS (staged one step
//     ahead), B streamed global->VGPR (no LDS), 2x unrolled. Barrier vmcnt(0)
//     drain now overlaps the full MFMA chain -> near-free.
// ---------------------------------------------------------------------------

#define B_   4
#define S_   2048
#define D_   1024
#define OUTD 1024
#define K2   2048   // 2*D

typedef unsigned short ushort_t;
typedef __bf16 bf16x8 __attribute__((ext_vector_type(8)));
typedef float  f32x4  __attribute__((ext_vector_type(4)));

__device__ __forceinline__ ushort_t f2bf(float f) {
    uint32_t u = __float_as_uint(f);
    uint32_t r = (u + 0x7FFFu + ((u >> 16) & 1u)) >> 16;   // RNE
    return (ushort_t)r;
}
__device__ __forceinline__ float bf2f(ushort_t h) {
    return __uint_as_float(((uint32_t)h) << 16);
}

// async global->LDS, 16B per lane; LDS dest = wave-uniform base + lane*16
__device__ __forceinline__ void ld16(const ushort_t* g, ushort_t* l) {
    __builtin_amdgcn_global_load_lds(
        (const __attribute__((address_space(1))) void*)g,
        (__attribute__((address_space(3))) void*)l, 16, 0, 0);
}

// --------------------------- elementwise prep ------------------------------

__global__ void k_split(const float4* __restrict__ src, const float4* __restrict__ tgt,
                        ushort4* __restrict__ sh, ushort4* __restrict__ sl,
                        ushort4* __restrict__ th, ushort4* __restrict__ tl,
                        ushort4* __restrict__ acat)
{
    const int64_t n4 = (int64_t)B_ * S_ * D_ / 4;
    for (int64_t i = (int64_t)blockIdx.x * blockDim.x + threadIdx.x; i < n4;
         i += (int64_t)gridDim.x * blockDim.x) {
        float4 s = src[i];
        ushort4 hs = {f2bf(s.x), f2bf(s.y), f2bf(s.z), f2bf(s.w)};
        sh[i] = hs;
        ushort4 ls = {f2bf(s.x - bf2f(hs.x)), f2bf(s.y - bf2f(hs.y)),
                      f2bf(s.z - bf2f(hs.z)), f2bf(s.w - bf2f(hs.w))};
        sl[i] = ls;
        float4 tv = tgt[i];
        ushort4 ht = {f2bf(tv.x), f2bf(tv.y), f2bf(tv.z), f2bf(tv.w)};
        th[i] = ht;
        ushort4 lt = {f2bf(tv.x - bf2f(ht.x)), f2bf(tv.y - bf2f(ht.y)),
                      f2bf(tv.z - bf2f(ht.z)), f2bf(tv.w - bf2f(ht.w))};
        tl[i] = lt;
        int64_t row = i >> 8;                 // 256 float4 per D_ row
        acat[row * 512 + 256 + (i & 255)] = ht;
    }
}

__global__ void k_wconv(const float4* __restrict__ W, ushort4* __restrict__ wb)
{
    const int64_t n4 = (int64_t)OUTD * K2 / 4;
    for (int64_t i = (int64_t)blockIdx.x * blockDim.x + threadIdx.x; i < n4;
         i += (int64_t)gridDim.x * blockDim.x) {
        float4 w = W[i];
        wb[i] = (ushort4){f2bf(w.x), f2bf(w.y), f2bf(w.z), f2bf(w.w)};
    }
}

// srcT[b,d,s] = bf16(src[b,s,d])  (for the NT form of GEMM2)
__global__ void k_transpose(const float* __restrict__ src, ushort_t* __restrict__ sT)
{
    __shared__ ushort_t tile[32][33];
    int b  = blockIdx.z;
    int d0 = blockIdx.x * 32, s0 = blockIdx.y * 32;
    int tx = threadIdx.x, ty = threadIdx.y;   // block (32,8)
#pragma unroll
    for (int i = 0; i < 4; i++) {
        int s = s0 + ty + i * 8;
        tile[ty + i * 8][tx] = f2bf(src[((int64_t)b * S_ + s) * D_ + d0 + tx]);
    }
    __syncthreads();
#pragma unroll
    for (int i = 0; i < 4; i++) {
        int d = d0 + ty + i * 8;
        sT[((int64_t)b * D_ + d) * S_ + s0 + tx] = tile[tx][ty + i * 8];
    }
}

// ------------------------------- GEMM 1 ------------------------------------
// L[b] = tgt[b] @ src[b]^T with split-bf16:  Ah*Bh + Ah*Bl + Al*Bh
// 128x128 tile, BK=32, 4 waves 2x2 of 64x64, 16x16x32 bf16 MFMA.
// A (tgt hi/lo): LDS double-buffered, staged one K-step ahead via ld16.
// B (src hi/lo): streamed global->VGPR per wave, prefetched one step ahead.
__launch_bounds__(256)
__global__ void k_gemm_logits(const ushort_t* __restrict__ Ah, const ushort_t* __restrict__ Al,
                              const ushort_t* __restrict__ Bh, const ushort_t* __restrict__ Bl,
                              float* __restrict__ C,
                              float* __restrict__ pm, float* __restrict__ ps)
{
    const int M = S_, N = S_, K = D_;
    int b = blockIdx.z;
    Ah += (int64_t)b * M * K;  Al += (int64_t)b * M * K;
    Bh += (int64_t)b * N * K;  Bl += (int64_t)b * N * K;
    C  += (int64_t)b * M * N;

    __shared__ __align__(16) ushort_t sAh[2][4096], sAl[2][4096];
    __shared__ float red_m[2][128], red_s[2][128];

    int t    = threadIdx.x;
    int m0   = blockIdx.y * 128, n0 = blockIdx.x * 128;
    int wave = t >> 6, lane = t & 63;
    int wr   = (wave >> 1) * 64, wc = (wave & 1) * 64;
    int l15  = lane & 15, quad = lane >> 4;

    f32x4 acc[4][4];
#pragma unroll
    for (int i = 0; i < 4; i++)
#pragma unroll
        for (int j = 0; j < 4; j++) acc[i][j] = (f32x4){0.f, 0.f, 0.f, 0.f};

    int srow = t >> 2;                               // 0..63
    int scol = (((t & 3) ^ ((t >> 3) & 3)) * 8);     // swizzled source chunk
    int slot8 = (quad ^ ((l15 >> 1) & 3)) * 8;       // swizzled read slot

    const int64_t ra0 = (int64_t)(m0 + srow) * K + scol;
    const int64_t ra1 = ra0 + (int64_t)64 * K;

    ushort_t* dAh0[2] = { sAh[0] + wave * 512, sAh[1] + wave * 512 };
    ushort_t* dAh1[2] = { sAh[0] + 2048 + wave * 512, sAh[1] + 2048 + wave * 512 };
    ushort_t* dAl0[2] = { sAl[0] + wave * 512, sAl[1] + wave * 512 };
    ushort_t* dAl1[2] = { sAl[0] + 2048 + wave * 512, sAl[1] + 2048 + wave * 512 };

    int64_t vb[4];
#pragma unroll
    for (int j = 0; j < 4; j++) vb[j] = (int64_t)(n0 + wc + j * 16 + l15) * K + quad * 8;

    bf16x8 b0h[4], b0l[4], b1h[4], b1l[4];

    auto stageA = [&](int k, int p) {
        ld16(Ah + ra0 + k, dAh0[p]);  ld16(Ah + ra1 + k, dAh1[p]);
        ld16(Al + ra0 + k, dAl0[p]);  ld16(Al + ra1 + k, dAl1[p]);
    };
    auto loadB = [&](int k, bf16x8* bh, bf16x8* bl) {
#pragma unroll
        for (int j = 0; j < 4; j++) {
            bh[j] = *(const bf16x8*)(Bh + vb[j] + k);
            bl[j] = *(const bf16x8*)(Bl + vb[j] + k);
        }
    };
    auto compute = [&](int p, bf16x8* bh, bf16x8* bl) {
        bf16x8 ah[4], al[4];
#pragma unroll
        for (int i = 0; i < 4; i++) {
            ah[i] = *(const bf16x8*)(&sAh[p][(wr + i * 16 + l15) * 32 + slot8]);
            al[i] = *(const bf16x8*)(&sAl[p][(wr + i * 16 + l15) * 32 + slot8]);
        }
#pragma unroll
        for (int i = 0; i < 4; i++)
#pragma unroll
            for (int j = 0; j < 4; j++) {
                acc[i][j] = __builtin_amdgcn_mfma_f32_16x16x32_bf16(ah[i], bh[j], acc[i][j], 0, 0, 0);
                acc[i][j] = __builtin_amdgcn_mfma_f32_16x16x32_bf16(ah[i], bl[j], acc[i][j], 0, 0, 0);
                acc[i][j] = __builtin_amdgcn_mfma_f32_16x16x32_bf16(al[i], bh[j], acc[i][j], 0, 0, 0);
            }
    };

    stageA(0, 0);
    loadB(0, b0h, b0l);
    __syncthreads();

    for (int k0 = 0; k0 < K; k0 += 64) {
        // substep A: compute k0 from buf0/b0, stage+prefetch k0+32 into buf1/b1
        stageA(k0 + 32, 1);
        loadB(k0 + 32, b1h, b1l);
        compute(0, b0h, b0l);
        __syncthreads();
        // substep B: compute k0+32 from buf1/b1, stage+prefetch next into buf0/b0
        int kn = (k0 + 64 < K) ? k0 + 64 : 0;
        stageA(kn, 0);
        loadB(kn, b0h, b0l);
        compute(1, b1h, b1l);
        __syncthreads();
    }

    // C store
#pragma unroll
    for (int i = 0; i < 4; i++) {
        int row_base = m0 + wr + i * 16 + quad * 4;
#pragma unroll
        for (int j = 0; j < 4; j++) {
            int col = n0 + wc + j * 16 + l15;
#pragma unroll
            for (int r = 0; r < 4; r++)
                C[(int64_t)(row_base + r) * N + col] = acc[i][j][r];
        }
    }

    // fused partial column stats (max & sumexp over this block's 128 rows)
    int rowhalf = wave >> 1;
#pragma unroll
    for (int j = 0; j < 4; j++) {
        float m = -3.0e38f;
#pragma unroll
        for (int i = 0; i < 4; i++)
#pragma unroll
            for (int r = 0; r < 4; r++) m = fmaxf(m, acc[i][j][r]);
        float s = 0.f;
#pragma unroll
        for (int i = 0; i < 4; i++)
#pragma unroll
            for (int r = 0; r < 4; r++) s += __expf(acc[i][j][r] - m);
#pragma unroll
        for (int d = 16; d <= 32; d <<= 1) {
            float m2 = __shfl_xor(m, d, 64);
            float s2 = __shfl_xor(s, d, 64);
            float nm = fmaxf(m, m2);
            s = s * __expf(m - nm) + s2 * __expf(m2 - nm);
            m = nm;
        }
        if (lane < 16) {
            red_m[rowhalf][wc + j * 16 + l15] = m;
            red_s[rowhalf][wc + j * 16 + l15] = s;
        }
    }
    __syncthreads();
    if (t < 128) {
        float ma = red_m[0][t], mb = red_m[1][t];
        float sa = red_s[0][t], sb = red_s[1][t];
        float m = fmaxf(ma, mb);
        float s = sa * __expf(ma - m) + sb * __expf(mb - m);
        int idx = blockIdx.y * (B_ * S_) + b * S_ + n0 + t;
        pm[idx] = m;
        ps[idx] = s;
    }
}

// --------------------------- column softmax --------------------------------

__global__ void k_colstats2(const float* __restrict__ pm, const float* __restrict__ ps,
                            float* __restrict__ cmax, float* __restrict__ cinv)
{
    int i = blockIdx.x * 256 + threadIdx.x;   // 8192
    float m = -3.0e38f;
#pragma unroll
    for (int c = 0; c < 16; c++) m = fmaxf(m, pm[c * (B_ * S_) + i]);
    float sum = 0.f;
#pragma unroll
    for (int c = 0; c < 16; c++) sum += ps[c * (B_ * S_) + i] * __expf(pm[c * (B_ * S_) + i] - m);
    cmax[i] = m;
    cinv[i] = 1.0f / sum;
}

__global__ void k_softmax_norm(float4* __restrict__ L, const float4* __restrict__ cmax4,
                               const float4* __restrict__ cinv4, ushort4* __restrict__ wbf)
{
    const int64_t n4 = (int64_t)B_ * S_ * S_ / 4;
    for (int64_t i = (int64_t)blockIdx.x * blockDim.x + threadIdx.x; i < n4;
         i += (int64_t)gridDim.x * blockDim.x) {
        int b  = (int)(i >> 20);
        int c4 = (int)(i & 511);
        float4 x  = L[i];
        float4 cm = cmax4[b * 512 + c4];
        float4 ci = cinv4[b * 512 + c4];
        float4 w;
        w.x = __expf(x.x - cm.x) * ci.x;
        w.y = __expf(x.y - cm.y) * ci.y;
        w.z = __expf(x.z - cm.z) * ci.z;
        w.w = __expf(x.w - cm.w) * ci.w;
        L[i] = w;
        wbf[i] = (ushort4){f2bf(w.x), f2bf(w.y), f2bf(w.z), f2bf(w.w)};
    }
}

// ------------------------------- GEMM 2 ------------------------------------
// weight_sum[b] = weight[b] @ src[b] -> NT with srcT [d, s]; A via LDS dbuf,
// B streamed to regs. Epilogue writes bf16 into A_cat[:, 0:1024].
__launch_bounds__(256)
__global__ void k_gemm_wsum(const ushort_t* __restrict__ Wt, const ushort_t* __restrict__ Bt,
                            ushort_t* __restrict__ acat)
{
    const int M = S_, N = D_, K = S_;
    int b = blockIdx.z;
    const ushort_t* A  = Wt + (int64_t)b * M * K;
    const ushort_t* Bm = Bt + (int64_t)b * N * K;

    __shared__ __align__(16) ushort_t sA[2][4096];

    int t    = threadIdx.x;
    int m0   = blockIdx.y * 128, n0 = blockIdx.x * 128;
    int wave = t >> 6, lane = t & 63;
    int wr   = (wave >> 1) * 64, wc = (wave & 1) * 64;
    int l15  = lane & 15, quad = lane >> 4;

    f32x4 acc[4][4];
#pragma unroll
    for (int i = 0; i < 4; i++)
#pragma unroll
        for (int j = 0; j < 4; j++) acc[i][j] = (f32x4){0.f, 0.f, 0.f, 0.f};

    int srow = t >> 2;
    int scol = (((t & 3) ^ ((t >> 3) & 3)) * 8);
    int slot8 = (quad ^ ((l15 >> 1) & 3)) * 8;

    const int64_t ra0 = (int64_t)(m0 + srow) * K + scol;
    const int64_t ra1 = ra0 + (int64_t)64 * K;
    ushort_t* dA0[2] = { sA[0] + wave * 512, sA[1] + wave * 512 };
    ushort_t* dA1[2] = { sA[0] + 2048 + wave * 512, sA[1] + 2048 + wave * 512 };

    int64_t vb[4];
#pragma unroll
    for (int j = 0; j < 4; j++) vb[j] = (int64_t)(n0 + wc + j * 16 + l15) * K + quad * 8;

    bf16x8 b0[4], b1[4];

    auto stageA = [&](int k, int p) {
        ld16(A + ra0 + k, dA0[p]);  ld16(A + ra1 + k, dA1[p]);
    };
    auto loadB = [&](int k, bf16x8* bb) {
#pragma unroll
        for (int j = 0; j < 4; j++) bb[j] = *(const bf16x8*)(Bm + vb[j] + k);
    };
    auto compute = [&](int p, bf16x8* bb) {
        bf16x8 af[4];
#pragma unroll
        for (int i = 0; i < 4; i++)
            af[i] = *(const bf16x8*)(&sA[p][(wr + i * 16 + l15) * 32 + slot8]);
#pragma unroll
        for (int i = 0; i < 4; i++)
#pragma unroll
            for (int j = 0; j < 4; j++)
                acc[i][j] = __builtin_amdgcn_mfma_f32_16x16x32_bf16(af[i], bb[j], acc[i][j], 0, 0, 0);
    };

    stageA(0, 0);
    loadB(0, b0);
    __syncthreads();

    for (int k0 = 0; k0 < K; k0 += 64) {
        stageA(k0 + 32, 1);
        loadB(k0 + 32, b1);
        compute(0, b0);
        __syncthreads();
        int kn = (k0 + 64 < K) ? k0 + 64 : 0;
        stageA(kn, 0);
        loadB(kn, b0);
        compute(1, b1);
        __syncthreads();
    }

#pragma unroll
    for (int i = 0; i < 4; i++) {
        int row_base = m0 + wr + i * 16 + quad * 4;
#pragma unroll
        for (int j = 0; j < 4; j++) {
            int col = n0 + wc + j * 16 + l15;
#pragma unroll
            for (int r = 0; r < 4; r++)
                acat[((int64_t)b * S_ + row_base + r) * K2 + col] = f2bf(acc[i][j][r]);
        }
    }
}

// ------------------------------- GEMM 3 ------------------------------------
// out = A_cat (8192x2048) @ W^T + bias; A via LDS dbuf, B (W bf16) streamed.
__launch_bounds__(256)
__global__ void k_gemm_out(const ushort_t* __restrict__ A, const ushort_t* __restrict__ Bw,
                           const float* __restrict__ bias, float* __restrict__ out)
{
    const int N = OUTD, K = K2;

    __shared__ __align__(16) ushort_t sA[2][4096];

    int t    = threadIdx.x;
    int m0   = blockIdx.y * 128, n0 = blockIdx.x * 128;
    int wave = t >> 6, lane = t & 63;
    int wr   = (wave >> 1) * 64, wc = (wave & 1) * 64;
    int l15  = lane & 15, quad = lane >> 4;

    f32x4 acc[4][4];
#pragma unroll
    for (int i = 0; i < 4; i++)
#pragma unroll
        for (int j = 0; j < 4; j++) acc[i][j] = (f32x4){0.f, 0.f, 0.f, 0.f};

    int srow = t >> 2;
    int scol = (((t & 3) ^ ((t >> 3) & 3)) * 8);
    int slot8 = (quad ^ ((l15 >> 1) & 3)) * 8;

    const int64_t ra0 = (int64_t)(m0 + srow) * K + scol;
    const int64_t ra1 = ra0 + (int64_t)64 * K;
    ushort_t* dA0[2] = { sA[0] + wave * 512, sA[1] + wave * 512 };
    ushort_t* dA1[2] = { sA[0] + 2048 + wave * 512, sA[1] + 2048 + wave * 512 };

    int64_t vb[4];
#pragma unroll
    for (int j = 0; j < 4; j++) vb[j] = (int64_t)(n0 + wc + j * 16 + l15) * K + quad * 8;

    bf16x8 b0[4], b1[4];

    auto stageA = [&](int k, int p) {
        ld16(A + ra0 + k, dA0[p]);  ld16(A + ra1 + k, dA1[p]);
    };
    auto loadB = [&](int k, bf16x8* bb) {
#pragma unroll
        for (int j = 0; j < 4; j++) bb[j] = *(const bf16x8*)(Bw + vb[j] + k);
    };
    auto compute = [&](int p, bf16x8* bb) {
        bf16x8 af[4];
#pragma unroll
        for (int i = 0; i < 4; i++)
            af[i] = *(const bf16x8*)(&sA[p][(wr + i * 16 + l15) * 32 + slot8]);
#pragma unroll
        for (int i = 0; i < 4; i++)
#pragma unroll
            for (int j = 0; j < 4; j++)
                acc[i][j] = __builtin_amdgcn_mfma_f32_16x16x32_bf16(af[i], bb[j], acc[i][j], 0, 0, 0);
    };

    stageA(0, 0);
    loadB(0, b0);
    __syncthreads();

    for (int k0 = 0; k0 < K; k0 += 64) {
        stageA(k0 + 32, 1);
        loadB(k0 + 32, b1);
        compute(0, b0);
        __syncthreads();
        int kn = (k0 + 64 < K) ? k0 + 64 : 0;
        stageA(kn, 0);
        loadB(kn, b0);
        compute(1, b1);
        __syncthreads();
    }

#pragma unroll
    for (int i = 0; i < 4; i++) {
        int row_base = m0 + wr + i * 16 + quad * 4;
#pragma unroll
        for (int j = 0; j < 4; j++) {
            int col = n0 + wc + j * 16 + l15;
            float bv = bias[col];
#pragma unroll
            for (int r = 0; r < 4; r++)
                out[(int64_t)(row_base + r) * N + col] = acc[i][j][r] + bv;
        }
    }
}

// ------------------------------- launcher ----------------------------------

extern "C" void kernel_launch(void* const* d_in, const int* in_sizes, int n_in,
                              void* d_out, int out_size, void* d_ws, size_t ws_size,
                              hipStream_t stream)
{
    const float* src  = (const float*)d_in[0];
    const float* tgt  = (const float*)d_in[1];
    const float* W    = (const float*)d_in[2];
    const float* bias = (const float*)d_in[3];

    float* out = (float*)d_out;                           // [4,2048,1024]
    float* Lw  = out + (size_t)B_ * S_ * OUTD;            // [4,2048,2048] logits -> weight

    char*  ws = (char*)d_ws;
    size_t o  = 0;
    auto take = [&](size_t bytes) -> char* {
        char* p = ws + o;
        o += (bytes + 255) & ~(size_t)255;
        return p;
    };
    const size_t ELEMS = (size_t)B_ * S_ * D_;            // 8,388,608
    ushort_t* sh   = (ushort_t*)take(ELEMS * 2);          // src hi
    ushort_t* sl   = (ushort_t*)take(ELEMS * 2);          // src lo
    ushort_t* th   = (ushort_t*)take(ELEMS * 2);          // tgt hi
    ushort_t* tl   = (ushort_t*)take(ELEMS * 2);          // tgt lo
    ushort_t* sT   = (ushort_t*)take(ELEMS * 2);          // srcT bf16 [b,d,s]
    ushort_t* wbf  = (ushort_t*)take((size_t)B_ * S_ * S_ * 2);   // weight bf16
    ushort_t* acat = (ushort_t*)take((size_t)B_ * S_ * K2 * 2);   // [ws | tgt] bf16
    ushort_t* wb   = (ushort_t*)take((size_t)OUTD * K2 * 2);      // W bf16
    float*    pm   = (float*)take(16 * (size_t)B_ * S_ * 4);
    float*    ps   = (float*)take(16 * (size_t)B_ * S_ * 4);
    float*    cmax = (float*)take((size_t)B_ * S_ * 4);
    float*    cinv = (float*)take((size_t)B_ * S_ * 4);
    (void)ws_size; (void)in_sizes; (void)n_in; (void)out_size;

    k_split<<<dim3(2048), dim3(256), 0, stream>>>((const float4*)src, (const float4*)tgt,
                                                  (ushort4*)sh, (ushort4*)sl,
                                                  (ushort4*)th, (ushort4*)tl, (ushort4*)acat);
    k_wconv<<<dim3(512), dim3(256), 0, stream>>>((const float4*)W, (ushort4*)wb);
    k_transpose<<<dim3(32, 64, 4), dim3(32, 8), 0, stream>>>(src, sT);

    k_gemm_logits<<<dim3(16, 16, 4), dim3(256), 0, stream>>>(th, tl, sh, sl, Lw, pm, ps);

    k_colstats2<<<dim3(32), dim3(256), 0, stream>>>(pm, ps, cmax, cinv);
    k_softmax_norm<<<dim3(2048), dim3(256), 0, stream>>>((float4*)Lw, (const float4*)cmax,
                                                         (const float4*)cinv, (ushort4*)wbf);

    k_gemm_wsum<<<dim3(8, 16, 4), dim3(256), 0, stream>>>(wbf, sT, acat);
    k_gemm_out<<<dim3(8, 64), dim3(256), 0, stream>>>(acat, wb, bias, out);
}

// Round 5
// 389.897 us; speedup vs baseline: 1.3349x; 1.3349x over previous
//
#include <hip/hip_runtime.h>
#include <stdint.h>

// ---------------------------------------------------------------------------
// Attention_18116172054662 on MI355X (gfx950)
//   L = tgt @ src^T  (2-term split-f16: (tgt_hi + tgt_lo) @ src_f16)
//   weight = softmax(L, axis=tgt)   -> second output (f32, in place in d_out)
//   weight_sum = weight @ src       (f16 MFMA, NT via pre-transposed src)
//   out = [weight_sum | tgt] @ W^T + b   (f16 MFMA NT)
// R1: global_load_lds width-16 staging, fused column stats, vectorized EW.
// R2: XOR swizzle (neutral/slightly negative -> dropped).
// R3: explicit dbuf + direct-B regs -> regressed (NT B uncoalesced). REVERTED.
// R5: all-f16 pipeline. f16 eps=2^-11 lets the logits GEMM drop from 3 MFMA
//     terms (bf16 split) to 2, and GEMM2/3 single-f16 cuts their rounding 8x.
// ---------------------------------------------------------------------------

#define B_   4
#define S_   2048
#define D_   1024
#define OUTD 1024
#define K2   2048   // 2*D

typedef unsigned short ushort_t;
typedef _Float16 half8 __attribute__((ext_vector_type(8)));
typedef float    f32x4 __attribute__((ext_vector_type(4)));

__device__ __forceinline__ ushort_t f2h(float f) {
    union { _Float16 h; ushort_t u; } v;
    v.h = (_Float16)f;                    // RNE
    return v.u;
}
__device__ __forceinline__ float h2f(ushort_t u) {
    union { _Float16 h; ushort_t u; } v;
    v.u = u;
    return (float)v.h;
}

// async global->LDS, 16B per lane; LDS dest = wave-uniform base + lane*16
__device__ __forceinline__ void ld16(const ushort_t* g, ushort_t* l) {
    __builtin_amdgcn_global_load_lds(
        (const __attribute__((address_space(1))) void*)g,
        (__attribute__((address_space(3))) void*)l, 16, 0, 0);
}

// --------------------------- elementwise prep ------------------------------

// src -> f16; tgt -> f16 hi + f16 lo; tgt_hi also into A_cat[:,1024:2048]
__global__ void k_split(const float4* __restrict__ src, const float4* __restrict__ tgt,
                        ushort4* __restrict__ sh,
                        ushort4* __restrict__ th, ushort4* __restrict__ tl,
                        ushort4* __restrict__ acat)
{
    const int64_t n4 = (int64_t)B_ * S_ * D_ / 4;
    for (int64_t i = (int64_t)blockIdx.x * blockDim.x + threadIdx.x; i < n4;
         i += (int64_t)gridDim.x * blockDim.x) {
        float4 s = src[i];
        sh[i] = (ushort4){f2h(s.x), f2h(s.y), f2h(s.z), f2h(s.w)};
        float4 tv = tgt[i];
        ushort4 ht = {f2h(tv.x), f2h(tv.y), f2h(tv.z), f2h(tv.w)};
        th[i] = ht;
        tl[i] = (ushort4){f2h(tv.x - h2f(ht.x)), f2h(tv.y - h2f(ht.y)),
                          f2h(tv.z - h2f(ht.z)), f2h(tv.w - h2f(ht.w))};
        int64_t row = i >> 8;                 // 256 float4 per D_ row
        acat[row * 512 + 256 + (i & 255)] = ht;
    }
}

__global__ void k_wconv(const float4* __restrict__ W, ushort4* __restrict__ wb)
{
    const int64_t n4 = (int64_t)OUTD * K2 / 4;
    for (int64_t i = (int64_t)blockIdx.x * blockDim.x + threadIdx.x; i < n4;
         i += (int64_t)gridDim.x * blockDim.x) {
        float4 w = W[i];
        wb[i] = (ushort4){f2h(w.x), f2h(w.y), f2h(w.z), f2h(w.w)};
    }
}

// srcT[b,d,s] = f16(src[b,s,d])  (for the NT form of GEMM2)
__global__ void k_transpose(const float* __restrict__ src, ushort_t* __restrict__ sT)
{
    __shared__ ushort_t tile[32][33];
    int b  = blockIdx.z;
    int d0 = blockIdx.x * 32, s0 = blockIdx.y * 32;
    int tx = threadIdx.x, ty = threadIdx.y;   // block (32,8)
#pragma unroll
    for (int i = 0; i < 4; i++) {
        int s = s0 + ty + i * 8;
        tile[ty + i * 8][tx] = f2h(src[((int64_t)b * S_ + s) * D_ + d0 + tx]);
    }
    __syncthreads();
#pragma unroll
    for (int i = 0; i < 4; i++) {
        int d = d0 + ty + i * 8;
        sT[((int64_t)b * D_ + d) * S_ + s0 + tx] = tile[tx][ty + i * 8];
    }
}

// ------------------------------- GEMM 1 ------------------------------------
// L[b] = tgt[b] @ src[b]^T, 2-term f16 split:  Ah*B + Al*B
// 128x128 tile, BK=32, 4 waves 2x2 of 64x64, 16x16x32 f16 MFMA.
// Epilogue: per-block (128-row chunk) column max/sumexp -> pm/ps.
__launch_bounds__(256)
__global__ void k_gemm_logits(const ushort_t* __restrict__ Ah, const ushort_t* __restrict__ Al,
                              const ushort_t* __restrict__ Bs,
                              float* __restrict__ C,
                              float* __restrict__ pm, float* __restrict__ ps)
{
    const int M = S_, N = S_, K = D_;
    int b = blockIdx.z;
    Ah += (int64_t)b * M * K;  Al += (int64_t)b * M * K;
    Bs += (int64_t)b * N * K;
    C  += (int64_t)b * M * N;

    __shared__ __align__(16) ushort_t sAh[128 * 32], sAl[128 * 32], sB[128 * 32];
    __shared__ float red_m[2][128], red_s[2][128];

    int t    = threadIdx.x;
    int m0   = blockIdx.y * 128, n0 = blockIdx.x * 128;
    int wave = t >> 6, lane = t & 63;
    int wr   = (wave >> 1) * 64, wc = (wave & 1) * 64;
    int l15  = lane & 15, quad = lane >> 4;

    f32x4 acc[4][4];
#pragma unroll
    for (int i = 0; i < 4; i++)
#pragma unroll
        for (int j = 0; j < 4; j++) acc[i][j] = (f32x4){0.f, 0.f, 0.f, 0.f};

    int srow = t >> 2;          // 0..63
    int scol = (t & 3) * 8;     // 0/8/16/24 (f16)

    const ushort_t* gAh0 = Ah + (int64_t)(m0 + srow) * K + scol;
    const ushort_t* gAh1 = gAh0 + (int64_t)64 * K;
    const ushort_t* gAl0 = Al + (int64_t)(m0 + srow) * K + scol;
    const ushort_t* gAl1 = gAl0 + (int64_t)64 * K;
    const ushort_t* gB0  = Bs + (int64_t)(n0 + srow) * K + scol;
    const ushort_t* gB1  = gB0 + (int64_t)64 * K;

    ushort_t* lAh0 = sAh + wave * 512;  ushort_t* lAh1 = sAh + 2048 + wave * 512;
    ushort_t* lAl0 = sAl + wave * 512;  ushort_t* lAl1 = sAl + 2048 + wave * 512;
    ushort_t* lB0  = sB  + wave * 512;  ushort_t* lB1  = sB  + 2048 + wave * 512;

    for (int k0 = 0; k0 < K; k0 += 32) {
        ld16(gAh0, lAh0);  ld16(gAh1, lAh1);
        ld16(gAl0, lAl0);  ld16(gAl1, lAl1);
        ld16(gB0,  lB0);   ld16(gB1,  lB1);
        gAh0 += 32; gAh1 += 32; gAl0 += 32; gAl1 += 32; gB0 += 32; gB1 += 32;
        __syncthreads();

        half8 ah[4], al[4], bf[4];
#pragma unroll
        for (int i = 0; i < 4; i++) {
            ah[i] = *(const half8*)(&sAh[(wr + i * 16 + l15) * 32 + quad * 8]);
            al[i] = *(const half8*)(&sAl[(wr + i * 16 + l15) * 32 + quad * 8]);
        }
#pragma unroll
        for (int j = 0; j < 4; j++)
            bf[j] = *(const half8*)(&sB[(wc + j * 16 + l15) * 32 + quad * 8]);
#pragma unroll
        for (int i = 0; i < 4; i++)
#pragma unroll
            for (int j = 0; j < 4; j++) {
                acc[i][j] = __builtin_amdgcn_mfma_f32_16x16x32_f16(ah[i], bf[j], acc[i][j], 0, 0, 0);
                acc[i][j] = __builtin_amdgcn_mfma_f32_16x16x32_f16(al[i], bf[j], acc[i][j], 0, 0, 0);
            }
        __syncthreads();
    }

    // C store
#pragma unroll
    for (int i = 0; i < 4; i++) {
        int row_base = m0 + wr + i * 16 + quad * 4;
#pragma unroll
        for (int j = 0; j < 4; j++) {
            int col = n0 + wc + j * 16 + l15;
#pragma unroll
            for (int r = 0; r < 4; r++)
                C[(int64_t)(row_base + r) * N + col] = acc[i][j][r];
        }
    }

    // fused partial column stats (max & sumexp over this block's 128 rows)
    int rowhalf = wave >> 1;
#pragma unroll
    for (int j = 0; j < 4; j++) {
        float m = -3.0e38f;
#pragma unroll
        for (int i = 0; i < 4; i++)
#pragma unroll
            for (int r = 0; r < 4; r++) m = fmaxf(m, acc[i][j][r]);
        float s = 0.f;
#pragma unroll
        for (int i = 0; i < 4; i++)
#pragma unroll
            for (int r = 0; r < 4; r++) s += __expf(acc[i][j][r] - m);
#pragma unroll
        for (int d = 16; d <= 32; d <<= 1) {
            float m2 = __shfl_xor(m, d, 64);
            float s2 = __shfl_xor(s, d, 64);
            float nm = fmaxf(m, m2);
            s = s * __expf(m - nm) + s2 * __expf(m2 - nm);
            m = nm;
        }
        if (lane < 16) {
            red_m[rowhalf][wc + j * 16 + l15] = m;
            red_s[rowhalf][wc + j * 16 + l15] = s;
        }
    }
    __syncthreads();
    if (t < 128) {
        float ma = red_m[0][t], mb = red_m[1][t];
        float sa = red_s[0][t], sb = red_s[1][t];
        float m = fmaxf(ma, mb);
        float s = sa * __expf(ma - m) + sb * __expf(mb - m);
        int idx = blockIdx.y * (B_ * S_) + b * S_ + n0 + t;
        pm[idx] = m;
        ps[idx] = s;
    }
}

// --------------------------- column softmax --------------------------------

__global__ void k_colstats2(const float* __restrict__ pm, const float* __restrict__ ps,
                            float* __restrict__ cmax, float* __restrict__ cinv)
{
    int i = blockIdx.x * 256 + threadIdx.x;   // 8192
    float m = -3.0e38f;
#pragma unroll
    for (int c = 0; c < 16; c++) m = fmaxf(m, pm[c * (B_ * S_) + i]);
    float sum = 0.f;
#pragma unroll
    for (int c = 0; c < 16; c++) sum += ps[c * (B_ * S_) + i] * __expf(pm[c * (B_ * S_) + i] - m);
    cmax[i] = m;
    cinv[i] = 1.0f / sum;
}

// weight = exp(L - cmax)/csum, in place; also emit f16 copy for GEMM2
__global__ void k_softmax_norm(float4* __restrict__ L, const float4* __restrict__ cmax4,
                               const float4* __restrict__ cinv4, ushort4* __restrict__ wbf)
{
    const int64_t n4 = (int64_t)B_ * S_ * S_ / 4;
    for (int64_t i = (int64_t)blockIdx.x * blockDim.x + threadIdx.x; i < n4;
         i += (int64_t)gridDim.x * blockDim.x) {
        int b  = (int)(i >> 20);
        int c4 = (int)(i & 511);
        float4 x  = L[i];
        float4 cm = cmax4[b * 512 + c4];
        float4 ci = cinv4[b * 512 + c4];
        float4 w;
        w.x = __expf(x.x - cm.x) * ci.x;
        w.y = __expf(x.y - cm.y) * ci.y;
        w.z = __expf(x.z - cm.z) * ci.z;
        w.w = __expf(x.w - cm.w) * ci.w;
        L[i] = w;
        wbf[i] = (ushort4){f2h(w.x), f2h(w.y), f2h(w.z), f2h(w.w)};
    }
}

// ------------------------------- GEMM 2 ------------------------------------
// weight_sum[b] = weight[b] (2048x2048) @ src[b] -> NT with srcT [d, s]
// epilogue writes f16 into A_cat[:, 0:1024]
__launch_bounds__(256)
__global__ void k_gemm_wsum(const ushort_t* __restrict__ Wt, const ushort_t* __restrict__ Bt,
                            ushort_t* __restrict__ acat)
{
    const int M = S_, N = D_, K = S_;
    int b = blockIdx.z;
    const ushort_t* A  = Wt + (int64_t)b * M * K;
    const ushort_t* Bm = Bt + (int64_t)b * N * K;

    __shared__ __align__(16) ushort_t sA[128 * 32], sB[128 * 32];

    int t    = threadIdx.x;
    int m0   = blockIdx.y * 128, n0 = blockIdx.x * 128;
    int wave = t >> 6, lane = t & 63;
    int wr   = (wave >> 1) * 64, wc = (wave & 1) * 64;
    int l15  = lane & 15, quad = lane >> 4;

    f32x4 acc[4][4];
#pragma unroll
    for (int i = 0; i < 4; i++)
#pragma unroll
        for (int j = 0; j < 4; j++) acc[i][j] = (f32x4){0.f, 0.f, 0.f, 0.f};

    int srow = t >> 2, scol = (t & 3) * 8;

    const ushort_t* gA0 = A  + (int64_t)(m0 + srow) * K + scol;
    const ushort_t* gA1 = gA0 + (int64_t)64 * K;
    const ushort_t* gB0 = Bm + (int64_t)(n0 + srow) * K + scol;
    const ushort_t* gB1 = gB0 + (int64_t)64 * K;
    ushort_t* lA0 = sA + wave * 512;  ushort_t* lA1 = sA + 2048 + wave * 512;
    ushort_t* lB0 = sB + wave * 512;  ushort_t* lB1 = sB + 2048 + wave * 512;

    for (int k0 = 0; k0 < K; k0 += 32) {
        ld16(gA0, lA0);  ld16(gA1, lA1);
        ld16(gB0, lB0);  ld16(gB1, lB1);
        gA0 += 32; gA1 += 32; gB0 += 32; gB1 += 32;
        __syncthreads();

        half8 af[4], bf[4];
#pragma unroll
        for (int i = 0; i < 4; i++) af[i] = *(const half8*)(&sA[(wr + i * 16 + l15) * 32 + quad * 8]);
#pragma unroll
        for (int j = 0; j < 4; j++) bf[j] = *(const half8*)(&sB[(wc + j * 16 + l15) * 32 + quad * 8]);
#pragma unroll
        for (int i = 0; i < 4; i++)
#pragma unroll
            for (int j = 0; j < 4; j++)
                acc[i][j] = __builtin_amdgcn_mfma_f32_16x16x32_f16(af[i], bf[j], acc[i][j], 0, 0, 0);
        __syncthreads();
    }

#pragma unroll
    for (int i = 0; i < 4; i++) {
        int row_base = m0 + wr + i * 16 + quad * 4;
#pragma unroll
        for (int j = 0; j < 4; j++) {
            int col = n0 + wc + j * 16 + l15;
#pragma unroll
            for (int r = 0; r < 4; r++)
                acat[((int64_t)b * S_ + row_base + r) * K2 + col] = f2h(acc[i][j][r]);
        }
    }
}

// ------------------------------- GEMM 3 ------------------------------------
// out = A_cat (8192x2048) @ W^T + bias   (NT, W row-major [1024, 2048])
__launch_bounds__(256)
__global__ void k_gemm_out(const ushort_t* __restrict__ A, const ushort_t* __restrict__ Bw,
                           const float* __restrict__ bias, float* __restrict__ out)
{
    const int N = OUTD, K = K2;

    __shared__ __align__(16) ushort_t sA[128 * 32], sB[128 * 32];

    int t    = threadIdx.x;
    int m0   = blockIdx.y * 128, n0 = blockIdx.x * 128;
    int wave = t >> 6, lane = t & 63;
    int wr   = (wave >> 1) * 64, wc = (wave & 1) * 64;
    int l15  = lane & 15, quad = lane >> 4;

    f32x4 acc[4][4];
#pragma unroll
    for (int i = 0; i < 4; i++)
#pragma unroll
        for (int j = 0; j < 4; j++) acc[i][j] = (f32x4){0.f, 0.f, 0.f, 0.f};

    int srow = t >> 2, scol = (t & 3) * 8;

    const ushort_t* gA0 = A  + (int64_t)(m0 + srow) * K + scol;
    const ushort_t* gA1 = gA0 + (int64_t)64 * K;
    const ushort_t* gB0 = Bw + (int64_t)(n0 + srow) * K + scol;
    const ushort_t* gB1 = gB0 + (int64_t)64 * K;
    ushort_t* lA0 = sA + wave * 512;  ushort_t* lA1 = sA + 2048 + wave * 512;
    ushort_t* lB0 = sB + wave * 512;  ushort_t* lB1 = sB + 2048 + wave * 512;

    for (int k0 = 0; k0 < K; k0 += 32) {
        ld16(gA0, lA0);  ld16(gA1, lA1);
        ld16(gB0, lB0);  ld16(gB1, lB1);
        gA0 += 32; gA1 += 32; gB0 += 32; gB1 += 32;
        __syncthreads();

        half8 af[4], bf[4];
#pragma unroll
        for (int i = 0; i < 4; i++) af[i] = *(const half8*)(&sA[(wr + i * 16 + l15) * 32 + quad * 8]);
#pragma unroll
        for (int j = 0; j < 4; j++) bf[j] = *(const half8*)(&sB[(wc + j * 16 + l15) * 32 + quad * 8]);
#pragma unroll
        for (int i = 0; i < 4; i++)
#pragma unroll
            for (int j = 0; j < 4; j++)
                acc[i][j] = __builtin_amdgcn_mfma_f32_16x16x32_f16(af[i], bf[j], acc[i][j], 0, 0, 0);
        __syncthreads();
    }

#pragma unroll
    for (int i = 0; i < 4; i++) {
        int row_base = m0 + wr + i * 16 + quad * 4;
#pragma unroll
        for (int j = 0; j < 4; j++) {
            int col = n0 + wc + j * 16 + l15;
            float bv = bias[col];
#pragma unroll
            for (int r = 0; r < 4; r++)
                out[(int64_t)(row_base + r) * N + col] = acc[i][j][r] + bv;
        }
    }
}

// ------------------------------- launcher ----------------------------------

extern "C" void kernel_launch(void* const* d_in, const int* in_sizes, int n_in,
                              void* d_out, int out_size, void* d_ws, size_t ws_size,
                              hipStream_t stream)
{
    const float* src  = (const float*)d_in[0];
    const float* tgt  = (const float*)d_in[1];
    const float* W    = (const float*)d_in[2];
    const float* bias = (const float*)d_in[3];

    float* out = (float*)d_out;                           // [4,2048,1024]
    float* Lw  = out + (size_t)B_ * S_ * OUTD;            // [4,2048,2048] logits -> weight

    char*  ws = (char*)d_ws;
    size_t o  = 0;
    auto take = [&](size_t bytes) -> char* {
        char* p = ws + o;
        o += (bytes + 255) & ~(size_t)255;
        return p;
    };
    const size_t ELEMS = (size_t)B_ * S_ * D_;            // 8,388,608
    ushort_t* sh   = (ushort_t*)take(ELEMS * 2);          // src f16
    ushort_t* th   = (ushort_t*)take(ELEMS * 2);          // tgt hi f16
    ushort_t* tl   = (ushort_t*)take(ELEMS * 2);          // tgt lo f16
    ushort_t* sT   = (ushort_t*)take(ELEMS * 2);          // srcT f16 [b,d,s]
    ushort_t* wbf  = (ushort_t*)take((size_t)B_ * S_ * S_ * 2);   // weight f16
    ushort_t* acat = (ushort_t*)take((size_t)B_ * S_ * K2 * 2);   // [ws | tgt] f16
    ushort_t* wb   = (ushort_t*)take((size_t)OUTD * K2 * 2);      // W f16
    float*    pm   = (float*)take(16 * (size_t)B_ * S_ * 4);
    float*    ps   = (float*)take(16 * (size_t)B_ * S_ * 4);
    float*    cmax = (float*)take((size_t)B_ * S_ * 4);
    float*    cinv = (float*)take((size_t)B_ * S_ * 4);
    (void)ws_size; (void)in_sizes; (void)n_in; (void)out_size;

    k_split<<<dim3(2048), dim3(256), 0, stream>>>((const float4*)src, (const float4*)tgt,
                                                  (ushort4*)sh, (ushort4*)th, (ushort4*)tl,
                                                  (ushort4*)acat);
    k_wconv<<<dim3(512), dim3(256), 0, stream>>>((const float4*)W, (ushort4*)wb);
    k_transpose<<<dim3(32, 64, 4), dim3(32, 8), 0, stream>>>(src, sT);

    k_gemm_logits<<<dim3(16, 16, 4), dim3(256), 0, stream>>>(th, tl, sh, Lw, pm, ps);

    k_colstats2<<<dim3(32), dim3(256), 0, stream>>>(pm, ps, cmax, cinv);
    k_softmax_norm<<<dim3(2048), dim3(256), 0, stream>>>((float4*)Lw, (const float4*)cmax,
                                                         (const float4*)cinv, (ushort4*)wbf);

    k_gemm_wsum<<<dim3(8, 16, 4), dim3(256), 0, stream>>>(wbf, sT, acat);
    k_gemm_out<<<dim3(8, 64), dim3(256), 0, stream>>>(acat, wb, bias, out);
}

// Round 6
// 378.211 us; speedup vs baseline: 1.3761x; 1.0309x over previous
//
#include <hip/hip_runtime.h>
#include <stdint.h>

// ---------------------------------------------------------------------------
// Attention_18116172054662 on MI355X (gfx950)
//   L = tgt @ src^T  (2-term split-f16: (tgt_hi + tgt_lo) @ src_f16)
//   weight = softmax(L, axis=tgt)   -> second output (f32, in place in d_out)
//   out = weight @ PT^T + Q + b  where  PT = W1 @ src^T,  Q = tgt @ W2^T
//     (associativity: (weight@src)@W1^T == weight@(src@W1^T); removes the
//      weight_sum materialization, the src transpose, and the acat buffer)
// R1: global_load_lds width-16 staging, fused column stats, vectorized EW.
// R2: XOR swizzle (neutral -> dropped).  R3: explicit dbuf (regressed, reverted).
// R5: all-f16 pipeline (2-term logits split).
// R6: algebraic restructure of the back half + BK=64 single-term GEMMs
//     (32 MFMA per wave per barrier drain, matching logits' density).
// ---------------------------------------------------------------------------

#define B_   4
#define S_   2048
#define D_   1024
#define OUTD 1024

typedef unsigned short ushort_t;
typedef _Float16 half8 __attribute__((ext_vector_type(8)));
typedef float    f32x4 __attribute__((ext_vector_type(4)));

__device__ __forceinline__ ushort_t f2h(float f) {
    union { _Float16 h; ushort_t u; } v;
    v.h = (_Float16)f;                    // RNE
    return v.u;
}
__device__ __forceinline__ float h2f(ushort_t u) {
    union { _Float16 h; ushort_t u; } v;
    v.u = u;
    return (float)v.h;
}

// async global->LDS, 16B per lane; LDS dest = wave-uniform base + lane*16
__device__ __forceinline__ void ld16(const ushort_t* g, ushort_t* l) {
    __builtin_amdgcn_global_load_lds(
        (const __attribute__((address_space(1))) void*)g,
        (__attribute__((address_space(3))) void*)l, 16, 0, 0);
}

// --------------------------- elementwise prep ------------------------------

// src -> f16; tgt -> f16 hi + f16 lo
__global__ void k_split(const float4* __restrict__ src, const float4* __restrict__ tgt,
                        ushort4* __restrict__ sh,
                        ushort4* __restrict__ th, ushort4* __restrict__ tl)
{
    const int64_t n4 = (int64_t)B_ * S_ * D_ / 4;
    for (int64_t i = (int64_t)blockIdx.x * blockDim.x + threadIdx.x; i < n4;
         i += (int64_t)gridDim.x * blockDim.x) {
        float4 s = src[i];
        sh[i] = (ushort4){f2h(s.x), f2h(s.y), f2h(s.z), f2h(s.w)};
        float4 tv = tgt[i];
        ushort4 ht = {f2h(tv.x), f2h(tv.y), f2h(tv.z), f2h(tv.w)};
        th[i] = ht;
        tl[i] = (ushort4){f2h(tv.x - h2f(ht.x)), f2h(tv.y - h2f(ht.y)),
                          f2h(tv.z - h2f(ht.z)), f2h(tv.w - h2f(ht.w))};
    }
}

__global__ void k_wconv(const float4* __restrict__ W, ushort4* __restrict__ wb)
{
    const int64_t n4 = (int64_t)OUTD * 2 * D_ / 4;
    for (int64_t i = (int64_t)blockIdx.x * blockDim.x + threadIdx.x; i < n4;
         i += (int64_t)gridDim.x * blockDim.x) {
        float4 w = W[i];
        wb[i] = (ushort4){f2h(w.x), f2h(w.y), f2h(w.z), f2h(w.w)};
    }
}

// ------------------------------- GEMM 1 ------------------------------------
// L[b] = tgt[b] @ src[b]^T, 2-term f16 split:  Ah*B + Al*B
// 128x128 tile, BK=32, 4 waves 2x2 of 64x64, 16x16x32 f16 MFMA.
// Epilogue: per-block (128-row chunk) column max/sumexp -> pm/ps.
__launch_bounds__(256)
__global__ void k_gemm_logits(const ushort_t* __restrict__ Ah, const ushort_t* __restrict__ Al,
                              const ushort_t* __restrict__ Bs,
                              float* __restrict__ C,
                              float* __restrict__ pm, float* __restrict__ ps)
{
    const int M = S_, N = S_, K = D_;
    int b = blockIdx.z;
    Ah += (int64_t)b * M * K;  Al += (int64_t)b * M * K;
    Bs += (int64_t)b * N * K;
    C  += (int64_t)b * M * N;

    __shared__ __align__(16) ushort_t sAh[128 * 32], sAl[128 * 32], sB[128 * 32];
    __shared__ float red_m[2][128], red_s[2][128];

    int t    = threadIdx.x;
    int m0   = blockIdx.y * 128, n0 = blockIdx.x * 128;
    int wave = t >> 6, lane = t & 63;
    int wr   = (wave >> 1) * 64, wc = (wave & 1) * 64;
    int l15  = lane & 15, quad = lane >> 4;

    f32x4 acc[4][4];
#pragma unroll
    for (int i = 0; i < 4; i++)
#pragma unroll
        for (int j = 0; j < 4; j++) acc[i][j] = (f32x4){0.f, 0.f, 0.f, 0.f};

    int srow = t >> 2;          // 0..63
    int scol = (t & 3) * 8;     // 0/8/16/24 (f16)

    const ushort_t* gAh0 = Ah + (int64_t)(m0 + srow) * K + scol;
    const ushort_t* gAh1 = gAh0 + (int64_t)64 * K;
    const ushort_t* gAl0 = Al + (int64_t)(m0 + srow) * K + scol;
    const ushort_t* gAl1 = gAl0 + (int64_t)64 * K;
    const ushort_t* gB0  = Bs + (int64_t)(n0 + srow) * K + scol;
    const ushort_t* gB1  = gB0 + (int64_t)64 * K;

    ushort_t* lAh0 = sAh + wave * 512;  ushort_t* lAh1 = sAh + 2048 + wave * 512;
    ushort_t* lAl0 = sAl + wave * 512;  ushort_t* lAl1 = sAl + 2048 + wave * 512;
    ushort_t* lB0  = sB  + wave * 512;  ushort_t* lB1  = sB  + 2048 + wave * 512;

    for (int k0 = 0; k0 < K; k0 += 32) {
        ld16(gAh0, lAh0);  ld16(gAh1, lAh1);
        ld16(gAl0, lAl0);  ld16(gAl1, lAl1);
        ld16(gB0,  lB0);   ld16(gB1,  lB1);
        gAh0 += 32; gAh1 += 32; gAl0 += 32; gAl1 += 32; gB0 += 32; gB1 += 32;
        __syncthreads();

        half8 ah[4], al[4], bf[4];
#pragma unroll
        for (int i = 0; i < 4; i++) {
            ah[i] = *(const half8*)(&sAh[(wr + i * 16 + l15) * 32 + quad * 8]);
            al[i] = *(const half8*)(&sAl[(wr + i * 16 + l15) * 32 + quad * 8]);
        }
#pragma unroll
        for (int j = 0; j < 4; j++)
            bf[j] = *(const half8*)(&sB[(wc + j * 16 + l15) * 32 + quad * 8]);
#pragma unroll
        for (int i = 0; i < 4; i++)
#pragma unroll
            for (int j = 0; j < 4; j++) {
                acc[i][j] = __builtin_amdgcn_mfma_f32_16x16x32_f16(ah[i], bf[j], acc[i][j], 0, 0, 0);
                acc[i][j] = __builtin_amdgcn_mfma_f32_16x16x32_f16(al[i], bf[j], acc[i][j], 0, 0, 0);
            }
        __syncthreads();
    }

    // C store
#pragma unroll
    for (int i = 0; i < 4; i++) {
        int row_base = m0 + wr + i * 16 + quad * 4;
#pragma unroll
        for (int j = 0; j < 4; j++) {
            int col = n0 + wc + j * 16 + l15;
#pragma unroll
            for (int r = 0; r < 4; r++)
                C[(int64_t)(row_base + r) * N + col] = acc[i][j][r];
        }
    }

    // fused partial column stats (max & sumexp over this block's 128 rows)
    int rowhalf = wave >> 1;
#pragma unroll
    for (int j = 0; j < 4; j++) {
        float m = -3.0e38f;
#pragma unroll
        for (int i = 0; i < 4; i++)
#pragma unroll
            for (int r = 0; r < 4; r++) m = fmaxf(m, acc[i][j][r]);
        float s = 0.f;
#pragma unroll
        for (int i = 0; i < 4; i++)
#pragma unroll
            for (int r = 0; r < 4; r++) s += __expf(acc[i][j][r] - m);
#pragma unroll
        for (int d = 16; d <= 32; d <<= 1) {
            float m2 = __shfl_xor(m, d, 64);
            float s2 = __shfl_xor(s, d, 64);
            float nm = fmaxf(m, m2);
            s = s * __expf(m - nm) + s2 * __expf(m2 - nm);
            m = nm;
        }
        if (lane < 16) {
            red_m[rowhalf][wc + j * 16 + l15] = m;
            red_s[rowhalf][wc + j * 16 + l15] = s;
        }
    }
    __syncthreads();
    if (t < 128) {
        float ma = red_m[0][t], mb = red_m[1][t];
        float sa = red_s[0][t], sb = red_s[1][t];
        float m = fmaxf(ma, mb);
        float s = sa * __expf(ma - m) + sb * __expf(mb - m);
        int idx = blockIdx.y * (B_ * S_) + b * S_ + n0 + t;
        pm[idx] = m;
        ps[idx] = s;
    }
}

// --------------------------- column softmax --------------------------------

__global__ void k_colstats2(const float* __restrict__ pm, const float* __restrict__ ps,
                            float* __restrict__ cmax, float* __restrict__ cinv)
{
    int i = blockIdx.x * 256 + threadIdx.x;   // 8192
    float m = -3.0e38f;
#pragma unroll
    for (int c = 0; c < 16; c++) m = fmaxf(m, pm[c * (B_ * S_) + i]);
    float sum = 0.f;
#pragma unroll
    for (int c = 0; c < 16; c++) sum += ps[c * (B_ * S_) + i] * __expf(pm[c * (B_ * S_) + i] - m);
    cmax[i] = m;
    cinv[i] = 1.0f / sum;
}

// weight = exp(L - cmax)/csum, in place; also emit f16 copy for the final GEMM
__global__ void k_softmax_norm(float4* __restrict__ L, const float4* __restrict__ cmax4,
                               const float4* __restrict__ cinv4, ushort4* __restrict__ wbf)
{
    const int64_t n4 = (int64_t)B_ * S_ * S_ / 4;
    for (int64_t i = (int64_t)blockIdx.x * blockDim.x + threadIdx.x; i < n4;
         i += (int64_t)gridDim.x * blockDim.x) {
        int b  = (int)(i >> 20);
        int c4 = (int)(i & 511);
        float4 x  = L[i];
        float4 cm = cmax4[b * 512 + c4];
        float4 ci = cinv4[b * 512 + c4];
        float4 w;
        w.x = __expf(x.x - cm.x) * ci.x;
        w.y = __expf(x.y - cm.y) * ci.y;
        w.z = __expf(x.z - cm.z) * ci.z;
        w.w = __expf(x.w - cm.w) * ci.w;
        L[i] = w;
        wbf[i] = (ushort4){f2h(w.x), f2h(w.y), f2h(w.z), f2h(w.w)};
    }
}

// --------------------- generic NT f16 GEMM, BK=64 --------------------------
// C[m][n] = sum_k A[m][k]*B[n][k], 128x128 tile, 4 waves, 16x16x32 f16 MFMA.
// 32 MFMA per wave per barrier (2 k-subtiles of 32). f16 output.
__launch_bounds__(256)
__global__ void k_gemm_nt_f16(const ushort_t* __restrict__ A, int lda, int64_t bsA,
                              const ushort_t* __restrict__ Bm, int ldb, int64_t bsB,
                              ushort_t* __restrict__ C, int ldc, int64_t bsC, int K)
{
    int b = blockIdx.z;
    A  += (int64_t)b * bsA;
    Bm += (int64_t)b * bsB;
    C  += (int64_t)b * bsC;

    __shared__ __align__(16) ushort_t sA[128 * 64], sB[128 * 64];

    int t    = threadIdx.x;
    int m0   = blockIdx.y * 128, n0 = blockIdx.x * 128;
    int wave = t >> 6, lane = t & 63;
    int wr   = (wave >> 1) * 64, wc = (wave & 1) * 64;
    int l15  = lane & 15, quad = lane >> 4;

    f32x4 acc[4][4];
#pragma unroll
    for (int i = 0; i < 4; i++)
#pragma unroll
        for (int j = 0; j < 4; j++) acc[i][j] = (f32x4){0.f, 0.f, 0.f, 0.f};

    int srow = t >> 3;          // 0..31
    int scol = (t & 7) * 8;     // 0..56 (f16)

    const ushort_t* gA = A  + (int64_t)(m0 + srow) * lda + scol;
    const ushort_t* gB = Bm + (int64_t)(n0 + srow) * ldb + scol;
    ushort_t* lA = sA + wave * 512;
    ushort_t* lB = sB + wave * 512;

    for (int k0 = 0; k0 < K; k0 += 64) {
#pragma unroll
        for (int j = 0; j < 4; j++) {
            ld16(gA + (int64_t)(j * 32) * lda + k0, lA + j * 2048);
            ld16(gB + (int64_t)(j * 32) * ldb + k0, lB + j * 2048);
        }
        __syncthreads();
#pragma unroll
        for (int ks = 0; ks < 64; ks += 32) {
            half8 af[4], bf[4];
#pragma unroll
            for (int i = 0; i < 4; i++)
                af[i] = *(const half8*)(&sA[(wr + i * 16 + l15) * 64 + ks + quad * 8]);
#pragma unroll
            for (int j = 0; j < 4; j++)
                bf[j] = *(const half8*)(&sB[(wc + j * 16 + l15) * 64 + ks + quad * 8]);
#pragma unroll
            for (int i = 0; i < 4; i++)
#pragma unroll
                for (int j = 0; j < 4; j++)
                    acc[i][j] = __builtin_amdgcn_mfma_f32_16x16x32_f16(af[i], bf[j], acc[i][j], 0, 0, 0);
        }
        __syncthreads();
    }

#pragma unroll
    for (int i = 0; i < 4; i++) {
        int row_base = m0 + wr + i * 16 + quad * 4;
#pragma unroll
        for (int j = 0; j < 4; j++) {
            int col = n0 + wc + j * 16 + l15;
#pragma unroll
            for (int r = 0; r < 4; r++)
                C[(int64_t)(row_base + r) * ldc + col] = f2h(acc[i][j][r]);
        }
    }
}

// --------------------------- final GEMM ------------------------------------
// out[b][t][n] = sum_s weight_f16[b][t][s]*PT[b][n][s] + Q[b][t][n] + bias[n]
// Same structure as k_gemm_nt_f16 (BK=64), f32 output with Q+bias epilogue.
__launch_bounds__(256)
__global__ void k_gemm_final(const ushort_t* __restrict__ Wt, const ushort_t* __restrict__ PT,
                             const ushort_t* __restrict__ Q, const float* __restrict__ bias,
                             float* __restrict__ out)
{
    const int K = S_, N = OUTD;
    int b = blockIdx.z;
    const ushort_t* A  = Wt + (int64_t)b * S_ * S_;
    const ushort_t* Bm = PT + (int64_t)b * OUTD * S_;
    const ushort_t* Qb = Q  + (int64_t)b * S_ * OUTD;
    float* Cb = out + (int64_t)b * S_ * OUTD;

    __shared__ __align__(16) ushort_t sA[128 * 64], sB[128 * 64];

    int t    = threadIdx.x;
    int m0   = blockIdx.y * 128, n0 = blockIdx.x * 128;
    int wave = t >> 6, lane = t & 63;
    int wr   = (wave >> 1) * 64, wc = (wave & 1) * 64;
    int l15  = lane & 15, quad = lane >> 4;

    f32x4 acc[4][4];
#pragma unroll
    for (int i = 0; i < 4; i++)
#pragma unroll
        for (int j = 0; j < 4; j++) acc[i][j] = (f32x4){0.f, 0.f, 0.f, 0.f};

    int srow = t >> 3;
    int scol = (t & 7) * 8;

    const ushort_t* gA = A  + (int64_t)(m0 + srow) * K + scol;
    const ushort_t* gB = Bm + (int64_t)(n0 + srow) * K + scol;
    ushort_t* lA = sA + wave * 512;
    ushort_t* lB = sB + wave * 512;

    for (int k0 = 0; k0 < K; k0 += 64) {
#pragma unroll
        for (int j = 0; j < 4; j++) {
            ld16(gA + (int64_t)(j * 32) * K + k0, lA + j * 2048);
            ld16(gB + (int64_t)(j * 32) * K + k0, lB + j * 2048);
        }
        __syncthreads();
#pragma unroll
        for (int ks = 0; ks < 64; ks += 32) {
            half8 af[4], bf[4];
#pragma unroll
            for (int i = 0; i < 4; i++)
                af[i] = *(const half8*)(&sA[(wr + i * 16 + l15) * 64 + ks + quad * 8]);
#pragma unroll
            for (int j = 0; j < 4; j++)
                bf[j] = *(const half8*)(&sB[(wc + j * 16 + l15) * 64 + ks + quad * 8]);
#pragma unroll
            for (int i = 0; i < 4; i++)
#pragma unroll
                for (int j = 0; j < 4; j++)
                    acc[i][j] = __builtin_amdgcn_mfma_f32_16x16x32_f16(af[i], bf[j], acc[i][j], 0, 0, 0);
        }
        __syncthreads();
    }

#pragma unroll
    for (int i = 0; i < 4; i++) {
        int row_base = m0 + wr + i * 16 + quad * 4;
#pragma unroll
        for (int j = 0; j < 4; j++) {
            int col = n0 + wc + j * 16 + l15;
            float bv = bias[col];
#pragma unroll
            for (int r = 0; r < 4; r++) {
                int64_t idx = (int64_t)(row_base + r) * N + col;
                Cb[idx] = acc[i][j][r] + h2f(Qb[idx]) + bv;
            }
        }
    }
}

// ------------------------------- launcher ----------------------------------

extern "C" void kernel_launch(void* const* d_in, const int* in_sizes, int n_in,
                              void* d_out, int out_size, void* d_ws, size_t ws_size,
                              hipStream_t stream)
{
    const float* src  = (const float*)d_in[0];
    const float* tgt  = (const float*)d_in[1];
    const float* W    = (const float*)d_in[2];
    const float* bias = (const float*)d_in[3];

    float* out = (float*)d_out;                           // [4,2048,1024]
    float* Lw  = out + (size_t)B_ * S_ * OUTD;            // [4,2048,2048] logits -> weight

    char*  ws = (char*)d_ws;
    size_t o  = 0;
    auto take = [&](size_t bytes) -> char* {
        char* p = ws + o;
        o += (bytes + 255) & ~(size_t)255;
        return p;
    };
    const size_t ELEMS = (size_t)B_ * S_ * D_;            // 8,388,608
    ushort_t* sh   = (ushort_t*)take(ELEMS * 2);          // src f16
    ushort_t* th   = (ushort_t*)take(ELEMS * 2);          // tgt hi f16
    ushort_t* tl   = (ushort_t*)take(ELEMS * 2);          // tgt lo f16
    ushort_t* wbf  = (ushort_t*)take((size_t)B_ * S_ * S_ * 2);     // weight f16
    ushort_t* wb   = (ushort_t*)take((size_t)OUTD * 2 * D_ * 2);    // W f16 [1024,2048]
    ushort_t* PT   = (ushort_t*)take((size_t)B_ * OUTD * S_ * 2);   // W1@src^T f16 [b,1024,2048]
    ushort_t* Qb   = (ushort_t*)take((size_t)B_ * S_ * OUTD * 2);   // tgt@W2^T f16 [b,2048,1024]
    float*    pm   = (float*)take(16 * (size_t)B_ * S_ * 4);
    float*    ps   = (float*)take(16 * (size_t)B_ * S_ * 4);
    float*    cmax = (float*)take((size_t)B_ * S_ * 4);
    float*    cinv = (float*)take((size_t)B_ * S_ * 4);
    (void)ws_size; (void)in_sizes; (void)n_in; (void)out_size;

    k_split<<<dim3(2048), dim3(256), 0, stream>>>((const float4*)src, (const float4*)tgt,
                                                  (ushort4*)sh, (ushort4*)th, (ushort4*)tl);
    k_wconv<<<dim3(512), dim3(256), 0, stream>>>((const float4*)W, (ushort4*)wb);

    // PT[b][n][s] = sum_d W1[n][d] * src[b][s][d]   (M=1024, N=2048, K=1024)
    k_gemm_nt_f16<<<dim3(16, 8, 4), dim3(256), 0, stream>>>(
        wb, 2 * D_, 0,
        sh, D_, (int64_t)S_ * D_,
        PT, S_, (int64_t)OUTD * S_, D_);

    // Q[b][t][n] = sum_d tgt[b][t][d] * W2[n][d]    (M=2048, N=1024, K=1024)
    k_gemm_nt_f16<<<dim3(8, 16, 4), dim3(256), 0, stream>>>(
        th, D_, (int64_t)S_ * D_,
        wb + D_, 2 * D_, 0,
        Qb, OUTD, (int64_t)S_ * OUTD, D_);

    k_gemm_logits<<<dim3(16, 16, 4), dim3(256), 0, stream>>>(th, tl, sh, Lw, pm, ps);

    k_colstats2<<<dim3(32), dim3(256), 0, stream>>>(pm, ps, cmax, cinv);
    k_softmax_norm<<<dim3(2048), dim3(256), 0, stream>>>((float4*)Lw, (const float4*)cmax,
                                                         (const float4*)cinv, (ushort4*)wbf);

    k_gemm_final<<<dim3(8, 16, 4), dim3(256), 0, stream>>>(wbf, PT, Qb, bias, out);
}

// Round 7
// 374.941 us; speedup vs baseline: 1.3881x; 1.0087x over previous
//
#include <hip/hip_runtime.h>
#include <stdint.h>

// ---------------------------------------------------------------------------
// Attention_18116172054662 on MI355X (gfx950)
//   L = tgt @ src^T  (2-term split-f16: (tgt_hi + tgt_lo) @ src_f16)
//   weight = softmax(L, axis=tgt)   -> second output (f32, in place in d_out)
//   out = weight @ PT^T + Q + b  where  PT = W1 @ src^T,  Q = tgt @ W2^T
// R1: global_load_lds width-16 staging, fused column stats, vectorized EW.
// R2: XOR swizzle on 32-wide tiles (neutral there -> dropped for logits).
// R3: explicit dbuf (regressed, reverted).  R5: all-f16 pipeline.
// R6: algebraic restructure (PT/Q/final), BK=64 GEMMs.
// R7: BK=64 tiles have 128B row stride == full bank wrap -> ~16-way phase
//     conflicts. XOR chunk swizzle (slot = chunk ^ (row&7)) in BK=64 kernels.
// ---------------------------------------------------------------------------

#define B_   4
#define S_   2048
#define D_   1024
#define OUTD 1024

typedef unsigned short ushort_t;
typedef _Float16 half8 __attribute__((ext_vector_type(8)));
typedef float    f32x4 __attribute__((ext_vector_type(4)));

__device__ __forceinline__ ushort_t f2h(float f) {
    union { _Float16 h; ushort_t u; } v;
    v.h = (_Float16)f;                    // RNE
    return v.u;
}
__device__ __forceinline__ float h2f(ushort_t u) {
    union { _Float16 h; ushort_t u; } v;
    v.u = u;
    return (float)v.h;
}

// async global->LDS, 16B per lane; LDS dest = wave-uniform base + lane*16
__device__ __forceinline__ void ld16(const ushort_t* g, ushort_t* l) {
    __builtin_amdgcn_global_load_lds(
        (const __attribute__((address_space(1))) void*)g,
        (__attribute__((address_space(3))) void*)l, 16, 0, 0);
}

// --------------------------- elementwise prep ------------------------------

// src -> f16; tgt -> f16 hi + f16 lo
__global__ void k_split(const float4* __restrict__ src, const float4* __restrict__ tgt,
                        ushort4* __restrict__ sh,
                        ushort4* __restrict__ th, ushort4* __restrict__ tl)
{
    const int64_t n4 = (int64_t)B_ * S_ * D_ / 4;
    for (int64_t i = (int64_t)blockIdx.x * blockDim.x + threadIdx.x; i < n4;
         i += (int64_t)gridDim.x * blockDim.x) {
        float4 s = src[i];
        sh[i] = (ushort4){f2h(s.x), f2h(s.y), f2h(s.z), f2h(s.w)};
        float4 tv = tgt[i];
        ushort4 ht = {f2h(tv.x), f2h(tv.y), f2h(tv.z), f2h(tv.w)};
        th[i] = ht;
        tl[i] = (ushort4){f2h(tv.x - h2f(ht.x)), f2h(tv.y - h2f(ht.y)),
                          f2h(tv.z - h2f(ht.z)), f2h(tv.w - h2f(ht.w))};
    }
}

__global__ void k_wconv(const float4* __restrict__ W, ushort4* __restrict__ wb)
{
    const int64_t n4 = (int64_t)OUTD * 2 * D_ / 4;
    for (int64_t i = (int64_t)blockIdx.x * blockDim.x + threadIdx.x; i < n4;
         i += (int64_t)gridDim.x * blockDim.x) {
        float4 w = W[i];
        wb[i] = (ushort4){f2h(w.x), f2h(w.y), f2h(w.z), f2h(w.w)};
    }
}

// ------------------------------- GEMM 1 ------------------------------------
// L[b] = tgt[b] @ src[b]^T, 2-term f16 split:  Ah*B + Al*B
// 128x128 tile, BK=32, 4 waves 2x2 of 64x64, 16x16x32 f16 MFMA.
// Epilogue: per-block (128-row chunk) column max/sumexp -> pm/ps.
__launch_bounds__(256)
__global__ void k_gemm_logits(const ushort_t* __restrict__ Ah, const ushort_t* __restrict__ Al,
                              const ushort_t* __restrict__ Bs,
                              float* __restrict__ C,
                              float* __restrict__ pm, float* __restrict__ ps)
{
    const int M = S_, N = S_, K = D_;
    int b = blockIdx.z;
    Ah += (int64_t)b * M * K;  Al += (int64_t)b * M * K;
    Bs += (int64_t)b * N * K;
    C  += (int64_t)b * M * N;

    __shared__ __align__(16) ushort_t sAh[128 * 32], sAl[128 * 32], sB[128 * 32];
    __shared__ float red_m[2][128], red_s[2][128];

    int t    = threadIdx.x;
    int m0   = blockIdx.y * 128, n0 = blockIdx.x * 128;
    int wave = t >> 6, lane = t & 63;
    int wr   = (wave >> 1) * 64, wc = (wave & 1) * 64;
    int l15  = lane & 15, quad = lane >> 4;

    f32x4 acc[4][4];
#pragma unroll
    for (int i = 0; i < 4; i++)
#pragma unroll
        for (int j = 0; j < 4; j++) acc[i][j] = (f32x4){0.f, 0.f, 0.f, 0.f};

    int srow = t >> 2;          // 0..63
    int scol = (t & 3) * 8;     // 0/8/16/24 (f16)

    const ushort_t* gAh0 = Ah + (int64_t)(m0 + srow) * K + scol;
    const ushort_t* gAh1 = gAh0 + (int64_t)64 * K;
    const ushort_t* gAl0 = Al + (int64_t)(m0 + srow) * K + scol;
    const ushort_t* gAl1 = gAl0 + (int64_t)64 * K;
    const ushort_t* gB0  = Bs + (int64_t)(n0 + srow) * K + scol;
    const ushort_t* gB1  = gB0 + (int64_t)64 * K;

    ushort_t* lAh0 = sAh + wave * 512;  ushort_t* lAh1 = sAh + 2048 + wave * 512;
    ushort_t* lAl0 = sAl + wave * 512;  ushort_t* lAl1 = sAl + 2048 + wave * 512;
    ushort_t* lB0  = sB  + wave * 512;  ushort_t* lB1  = sB  + 2048 + wave * 512;

    for (int k0 = 0; k0 < K; k0 += 32) {
        ld16(gAh0, lAh0);  ld16(gAh1, lAh1);
        ld16(gAl0, lAl0);  ld16(gAl1, lAl1);
        ld16(gB0,  lB0);   ld16(gB1,  lB1);
        gAh0 += 32; gAh1 += 32; gAl0 += 32; gAl1 += 32; gB0 += 32; gB1 += 32;
        __syncthreads();

        half8 ah[4], al[4], bf[4];
#pragma unroll
        for (int i = 0; i < 4; i++) {
            ah[i] = *(const half8*)(&sAh[(wr + i * 16 + l15) * 32 + quad * 8]);
            al[i] = *(const half8*)(&sAl[(wr + i * 16 + l15) * 32 + quad * 8]);
        }
#pragma unroll
        for (int j = 0; j < 4; j++)
            bf[j] = *(const half8*)(&sB[(wc + j * 16 + l15) * 32 + quad * 8]);
#pragma unroll
        for (int i = 0; i < 4; i++)
#pragma unroll
            for (int j = 0; j < 4; j++) {
                acc[i][j] = __builtin_amdgcn_mfma_f32_16x16x32_f16(ah[i], bf[j], acc[i][j], 0, 0, 0);
                acc[i][j] = __builtin_amdgcn_mfma_f32_16x16x32_f16(al[i], bf[j], acc[i][j], 0, 0, 0);
            }
        __syncthreads();
    }

    // C store
#pragma unroll
    for (int i = 0; i < 4; i++) {
        int row_base = m0 + wr + i * 16 + quad * 4;
#pragma unroll
        for (int j = 0; j < 4; j++) {
            int col = n0 + wc + j * 16 + l15;
#pragma unroll
            for (int r = 0; r < 4; r++)
                C[(int64_t)(row_base + r) * N + col] = acc[i][j][r];
        }
    }

    // fused partial column stats (max & sumexp over this block's 128 rows)
    int rowhalf = wave >> 1;
#pragma unroll
    for (int j = 0; j < 4; j++) {
        float m = -3.0e38f;
#pragma unroll
        for (int i = 0; i < 4; i++)
#pragma unroll
            for (int r = 0; r < 4; r++) m = fmaxf(m, acc[i][j][r]);
        float s = 0.f;
#pragma unroll
        for (int i = 0; i < 4; i++)
#pragma unroll
            for (int r = 0; r < 4; r++) s += __expf(acc[i][j][r] - m);
#pragma unroll
        for (int d = 16; d <= 32; d <<= 1) {
            float m2 = __shfl_xor(m, d, 64);
            float s2 = __shfl_xor(s, d, 64);
            float nm = fmaxf(m, m2);
            s = s * __expf(m - nm) + s2 * __expf(m2 - nm);
            m = nm;
        }
        if (lane < 16) {
            red_m[rowhalf][wc + j * 16 + l15] = m;
            red_s[rowhalf][wc + j * 16 + l15] = s;
        }
    }
    __syncthreads();
    if (t < 128) {
        float ma = red_m[0][t], mb = red_m[1][t];
        float sa = red_s[0][t], sb = red_s[1][t];
        float m = fmaxf(ma, mb);
        float s = sa * __expf(ma - m) + sb * __expf(mb - m);
        int idx = blockIdx.y * (B_ * S_) + b * S_ + n0 + t;
        pm[idx] = m;
        ps[idx] = s;
    }
}

// --------------------------- column softmax --------------------------------

__global__ void k_colstats2(const float* __restrict__ pm, const float* __restrict__ ps,
                            float* __restrict__ cmax, float* __restrict__ cinv)
{
    int i = blockIdx.x * 256 + threadIdx.x;   // 8192
    float m = -3.0e38f;
#pragma unroll
    for (int c = 0; c < 16; c++) m = fmaxf(m, pm[c * (B_ * S_) + i]);
    float sum = 0.f;
#pragma unroll
    for (int c = 0; c < 16; c++) sum += ps[c * (B_ * S_) + i] * __expf(pm[c * (B_ * S_) + i] - m);
    cmax[i] = m;
    cinv[i] = 1.0f / sum;
}

// weight = exp(L - cmax)/csum, in place; also emit f16 copy for the final GEMM
__global__ void k_softmax_norm(float4* __restrict__ L, const float4* __restrict__ cmax4,
                               const float4* __restrict__ cinv4, ushort4* __restrict__ wbf)
{
    const int64_t n4 = (int64_t)B_ * S_ * S_ / 4;
    for (int64_t i = (int64_t)blockIdx.x * blockDim.x + threadIdx.x; i < n4;
         i += (int64_t)gridDim.x * blockDim.x) {
        int b  = (int)(i >> 20);
        int c4 = (int)(i & 511);
        float4 x  = L[i];
        float4 cm = cmax4[b * 512 + c4];
        float4 ci = cinv4[b * 512 + c4];
        float4 w;
        w.x = __expf(x.x - cm.x) * ci.x;
        w.y = __expf(x.y - cm.y) * ci.y;
        w.z = __expf(x.z - cm.z) * ci.z;
        w.w = __expf(x.w - cm.w) * ci.w;
        L[i] = w;
        wbf[i] = (ushort4){f2h(w.x), f2h(w.y), f2h(w.z), f2h(w.w)};
    }
}

// --------------------- generic NT f16 GEMM, BK=64 --------------------------
// C[m][n] = sum_k A[m][k]*B[n][k], 128x128 tile, 4 waves, 16x16x32 f16 MFMA.
// XOR chunk swizzle: LDS chunk s of row r holds global chunk s ^ (r&7).
__launch_bounds__(256)
__global__ void k_gemm_nt_f16(const ushort_t* __restrict__ A, int lda, int64_t bsA,
                              const ushort_t* __restrict__ Bm, int ldb, int64_t bsB,
                              ushort_t* __restrict__ C, int ldc, int64_t bsC, int K)
{
    int b = blockIdx.z;
    A  += (int64_t)b * bsA;
    Bm += (int64_t)b * bsB;
    C  += (int64_t)b * bsC;

    __shared__ __align__(16) ushort_t sA[128 * 64], sB[128 * 64];

    int t    = threadIdx.x;
    int m0   = blockIdx.y * 128, n0 = blockIdx.x * 128;
    int wave = t >> 6, lane = t & 63;
    int wr   = (wave >> 1) * 64, wc = (wave & 1) * 64;
    int l15  = lane & 15, quad = lane >> 4;
    int e7   = l15 & 7;

    f32x4 acc[4][4];
#pragma unroll
    for (int i = 0; i < 4; i++)
#pragma unroll
        for (int j = 0; j < 4; j++) acc[i][j] = (f32x4){0.f, 0.f, 0.f, 0.f};

    int srow = t >> 3;                                // 0..31
    int scol = (((t & 7) ^ (srow & 7)) * 8);          // swizzled global chunk

    const ushort_t* gA = A  + (int64_t)(m0 + srow) * lda + scol;
    const ushort_t* gB = Bm + (int64_t)(n0 + srow) * ldb + scol;
    ushort_t* lA = sA + wave * 512;
    ushort_t* lB = sB + wave * 512;

    for (int k0 = 0; k0 < K; k0 += 64) {
#pragma unroll
        for (int j = 0; j < 4; j++) {
            ld16(gA + (int64_t)(j * 32) * lda + k0, lA + j * 2048);
            ld16(gB + (int64_t)(j * 32) * ldb + k0, lB + j * 2048);
        }
        __syncthreads();
#pragma unroll
        for (int ks = 0; ks < 64; ks += 32) {
            int gchunk = (ks >> 3) + quad;            // 0..7
            int slot   = (gchunk ^ e7) * 8;
            half8 af[4], bf[4];
#pragma unroll
            for (int i = 0; i < 4; i++)
                af[i] = *(const half8*)(&sA[(wr + i * 16 + l15) * 64 + slot]);
#pragma unroll
            for (int j = 0; j < 4; j++)
                bf[j] = *(const half8*)(&sB[(wc + j * 16 + l15) * 64 + slot]);
#pragma unroll
            for (int i = 0; i < 4; i++)
#pragma unroll
                for (int j = 0; j < 4; j++)
                    acc[i][j] = __builtin_amdgcn_mfma_f32_16x16x32_f16(af[i], bf[j], acc[i][j], 0, 0, 0);
        }
        __syncthreads();
    }

#pragma unroll
    for (int i = 0; i < 4; i++) {
        int row_base = m0 + wr + i * 16 + quad * 4;
#pragma unroll
        for (int j = 0; j < 4; j++) {
            int col = n0 + wc + j * 16 + l15;
#pragma unroll
            for (int r = 0; r < 4; r++)
                C[(int64_t)(row_base + r) * ldc + col] = f2h(acc[i][j][r]);
        }
    }
}

// --------------------------- final GEMM ------------------------------------
// out[b][t][n] = sum_s weight_f16[b][t][s]*PT[b][n][s] + Q[b][t][n] + bias[n]
// Same BK=64 structure + XOR chunk swizzle; f32 output with Q+bias epilogue.
__launch_bounds__(256)
__global__ void k_gemm_final(const ushort_t* __restrict__ Wt, const ushort_t* __restrict__ PT,
                             const ushort_t* __restrict__ Q, const float* __restrict__ bias,
                             float* __restrict__ out)
{
    const int K = S_, N = OUTD;
    int b = blockIdx.z;
    const ushort_t* A  = Wt + (int64_t)b * S_ * S_;
    const ushort_t* Bm = PT + (int64_t)b * OUTD * S_;
    const ushort_t* Qb = Q  + (int64_t)b * S_ * OUTD;
    float* Cb = out + (int64_t)b * S_ * OUTD;

    __shared__ __align__(16) ushort_t sA[128 * 64], sB[128 * 64];

    int t    = threadIdx.x;
    int m0   = blockIdx.y * 128, n0 = blockIdx.x * 128;
    int wave = t >> 6, lane = t & 63;
    int wr   = (wave >> 1) * 64, wc = (wave & 1) * 64;
    int l15  = lane & 15, quad = lane >> 4;
    int e7   = l15 & 7;

    f32x4 acc[4][4];
#pragma unroll
    for (int i = 0; i < 4; i++)
#pragma unroll
        for (int j = 0; j < 4; j++) acc[i][j] = (f32x4){0.f, 0.f, 0.f, 0.f};

    int srow = t >> 3;
    int scol = (((t & 7) ^ (srow & 7)) * 8);

    const ushort_t* gA = A  + (int64_t)(m0 + srow) * K + scol;
    const ushort_t* gB = Bm + (int64_t)(n0 + srow) * K + scol;
    ushort_t* lA = sA + wave * 512;
    ushort_t* lB = sB + wave * 512;

    for (int k0 = 0; k0 < K; k0 += 64) {
#pragma unroll
        for (int j = 0; j < 4; j++) {
            ld16(gA + (int64_t)(j * 32) * K + k0, lA + j * 2048);
            ld16(gB + (int64_t)(j * 32) * K + k0, lB + j * 2048);
        }
        __syncthreads();
#pragma unroll
        for (int ks = 0; ks < 64; ks += 32) {
            int gchunk = (ks >> 3) + quad;
            int slot   = (gchunk ^ e7) * 8;
            half8 af[4], bf[4];
#pragma unroll
            for (int i = 0; i < 4; i++)
                af[i] = *(const half8*)(&sA[(wr + i * 16 + l15) * 64 + slot]);
#pragma unroll
            for (int j = 0; j < 4; j++)
                bf[j] = *(const half8*)(&sB[(wc + j * 16 + l15) * 64 + slot]);
#pragma unroll
            for (int i = 0; i < 4; i++)
#pragma unroll
                for (int j = 0; j < 4; j++)
                    acc[i][j] = __builtin_amdgcn_mfma_f32_16x16x32_f16(af[i], bf[j], acc[i][j], 0, 0, 0);
        }
        __syncthreads();
    }

#pragma unroll
    for (int i = 0; i < 4; i++) {
        int row_base = m0 + wr + i * 16 + quad * 4;
#pragma unroll
        for (int j = 0; j < 4; j++) {
            int col = n0 + wc + j * 16 + l15;
            float bv = bias[col];
#pragma unroll
            for (int r = 0; r < 4; r++) {
                int64_t idx = (int64_t)(row_base + r) * N + col;
                Cb[idx] = acc[i][j][r] + h2f(Qb[idx]) + bv;
            }
        }
    }
}

// ------------------------------- launcher ----------------------------------

extern "C" void kernel_launch(void* const* d_in, const int* in_sizes, int n_in,
                              void* d_out, int out_size, void* d_ws, size_t ws_size,
                              hipStream_t stream)
{
    const float* src  = (const float*)d_in[0];
    const float* tgt  = (const float*)d_in[1];
    const float* W    = (const float*)d_in[2];
    const float* bias = (const float*)d_in[3];

    float* out = (float*)d_out;                           // [4,2048,1024]
    float* Lw  = out + (size_t)B_ * S_ * OUTD;            // [4,2048,2048] logits -> weight

    char*  ws = (char*)d_ws;
    size_t o  = 0;
    auto take = [&](size_t bytes) -> char* {
        char* p = ws + o;
        o += (bytes + 255) & ~(size_t)255;
        return p;
    };
    const size_t ELEMS = (size_t)B_ * S_ * D_;            // 8,388,608
    ushort_t* sh   = (ushort_t*)take(ELEMS * 2);          // src f16
    ushort_t* th   = (ushort_t*)take(ELEMS * 2);          // tgt hi f16
    ushort_t* tl   = (ushort_t*)take(ELEMS * 2);          // tgt lo f16
    ushort_t* wbf  = (ushort_t*)take((size_t)B_ * S_ * S_ * 2);     // weight f16
    ushort_t* wb   = (ushort_t*)take((size_t)OUTD * 2 * D_ * 2);    // W f16 [1024,2048]
    ushort_t* PT   = (ushort_t*)take((size_t)B_ * OUTD * S_ * 2);   // W1@src^T f16 [b,1024,2048]
    ushort_t* Qb   = (ushort_t*)take((size_t)B_ * S_ * OUTD * 2);   // tgt@W2^T f16 [b,2048,1024]
    float*    pm   = (float*)take(16 * (size_t)B_ * S_ * 4);
    float*    ps   = (float*)take(16 * (size_t)B_ * S_ * 4);
    float*    cmax = (float*)take((size_t)B_ * S_ * 4);
    float*    cinv = (float*)take((size_t)B_ * S_ * 4);
    (void)ws_size; (void)in_sizes; (void)n_in; (void)out_size;

    k_split<<<dim3(2048), dim3(256), 0, stream>>>((const float4*)src, (const float4*)tgt,
                                                  (ushort4*)sh, (ushort4*)th, (ushort4*)tl);
    k_wconv<<<dim3(512), dim3(256), 0, stream>>>((const float4*)W, (ushort4*)wb);

    // PT[b][n][s] = sum_d W1[n][d] * src[b][s][d]   (M=1024, N=2048, K=1024)
    k_gemm_nt_f16<<<dim3(16, 8, 4), dim3(256), 0, stream>>>(
        wb, 2 * D_, 0,
        sh, D_, (int64_t)S_ * D_,
        PT, S_, (int64_t)OUTD * S_, D_);

    // Q[b][t][n] = sum_d tgt[b][t][d] * W2[n][d]    (M=2048, N=1024, K=1024)
    k_gemm_nt_f16<<<dim3(8, 16, 4), dim3(256), 0, stream>>>(
        th, D_, (int64_t)S_ * D_,
        wb + D_, 2 * D_, 0,
        Qb, OUTD, (int64_t)S_ * OUTD, D_);

    k_gemm_logits<<<dim3(16, 16, 4), dim3(256), 0, stream>>>(th, tl, sh, Lw, pm, ps);

    k_colstats2<<<dim3(32), dim3(256), 0, stream>>>(pm, ps, cmax, cinv);
    k_softmax_norm<<<dim3(2048), dim3(256), 0, stream>>>((float4*)Lw, (const float4*)cmax,
                                                         (const float4*)cinv, (ushort4*)wbf);

    k_gemm_final<<<dim3(8, 16, 4), dim3(256), 0, stream>>>(wbf, PT, Qb, bias, out);
}